// Round 6
// baseline (560.839 us; speedup 1.0000x reference)
//
#include <hip/hip_runtime.h>

#define LOG2E 1.4426950408889634f
#define ATTN_SCALE 0.08838834764831843f   // 1/sqrt(128)

using bhalf8 = __attribute__((ext_vector_type(8))) short;  // 8 bf16 in 4 VGPRs
using f32x4  = __attribute__((ext_vector_type(4))) float;  // MFMA accumulator

// round-to-nearest-even fp32 -> bf16
__device__ __forceinline__ unsigned short f2bf(float f) {
  unsigned u = __float_as_uint(f);
  u += 0x7fffu + ((u >> 16) & 1u);
  return (unsigned short)(u >> 16);
}

// pack two fp32 -> bf16x2 (round-half-up) with one v_perm_b32
__device__ __forceinline__ unsigned pack_bf16_2(float lo, float hi) {
  unsigned a = __float_as_uint(lo) + 0x8000u;
  unsigned b = __float_as_uint(hi) + 0x8000u;
  return __builtin_amdgcn_perm(b, a, 0x07060302);  // D = {b.hi16, a.hi16}
}

// async global->LDS DMA, 16B per lane; lds dest must be wave-uniform base
__device__ __forceinline__ void gl_lds16(const unsigned short* g, unsigned short* l) {
  __builtin_amdgcn_global_load_lds(
      (const __attribute__((address_space(1))) void*)g,
      (__attribute__((address_space(3))) void*)l, 16, 0, 0);
}

// ---------------- fp32 -> bf16 convert, 4 elems/thread ----------------
__global__ void cvt_kernel(const float* __restrict__ src,
                           unsigned short* __restrict__ dst, int n4) {
  int i = blockIdx.x * blockDim.x + threadIdx.x;
  if (i >= n4) return;
  float4 f = reinterpret_cast<const float4*>(src)[i];
  unsigned lo = (unsigned)f2bf(f.x) | ((unsigned)f2bf(f.y) << 16);
  unsigned hi = (unsigned)f2bf(f.z) | ((unsigned)f2bf(f.w) << 16);
  reinterpret_cast<uint2*>(dst)[i] = make_uint2(lo, hi);
}

// =====================================================================
// 128x256-tile GEMM, BK=32, C = A[M,2048] * Bt[N,2048]^T
// R6: occupancy-driven overlap. LDS 48 KiB/block (2buf x (128+256)x32x2B),
// acc 4x4 = 64 VGPR/wave, __launch_bounds__(512,4) -> 2 blocks/CU,
// 4 waves/SIMD: one block's vmcnt+barrier drain overlaps the other block's
// MFMAs (m97 implicit-TLP mechanism; m233: the drain can't be hidden
// in-wave in a 2-phase loop). Grid 8x64 = 512 blocks = 2/CU, no tail.
// Subtile LDS layout: [nsub][512] elems, subtile = 16 rows x 32 k, element
// (r,c) at r*32 + (c ^ ((r>>3)<<4)) (st_16x32 swizzle, m201); staging writes
// linearly via global_load_lds from pre-swizzled global addresses.
// 2 barriers/K-tile; counted vmcnt(3) (3 loads/tile, 2 tiles in flight).
// T1 XCD remap: XCD k owns rows 8k..8k+7 x all 8 cols.
// MODE 0: bf16 out, split heads [b,h,s,d]   (Q, K projections)
// MODE 1: bf16 out, transposed [b,h,d,s]    (V projection; MFMA swapped)
// MODE 2: fp32 out + bias, row-major [M,N]  (output projection)
// =====================================================================
#define GBAR()  asm volatile("s_barrier" ::: "memory")

// stage one K-tile (A: 128x32 = 512 chunks, 1/thread; B: 256x32 = 1024, 2/thread)
__device__ __forceinline__ void stage32(
    const unsigned short* __restrict__ A, const unsigned short* __restrict__ Bt,
    unsigned short* as_, unsigned short* bs_, int ks, int row0, int col0,
    int wave, int rA, int cA, const int (&rB)[2], const int (&cB)[2]) {
  gl_lds16(A  + (size_t)(row0 + rA)    * 2048 + ks + cA,    as_ + wave * 512);
  gl_lds16(Bt + (size_t)(col0 + rB[0]) * 2048 + ks + cB[0], bs_ + wave * 512);
  gl_lds16(Bt + (size_t)(col0 + rB[1]) * 2048 + ks + cB[1], bs_ + 4096 + wave * 512);
}

template <int MODE>
__device__ __forceinline__ void ktile32(
    const unsigned short* __restrict__ A, const unsigned short* __restrict__ Bt,
    const unsigned short* as_, const unsigned short* bs_,
    unsigned short* as_w, unsigned short* bs_w, int ks,
    int row0, int col0, int wave, int wr, int wc, int rbase,
    int rA, int cA, const int (&rB)[2], const int (&cB)[2],
    f32x4 (&acc)[4][4]) {
  bhalf8 af[4], bf[4];
#pragma unroll
  for (int i = 0; i < 4; ++i)
    af[i] = *reinterpret_cast<const bhalf8*>(as_ + (wr * 4 + i) * 512 + rbase);
#pragma unroll
  for (int j = 0; j < 4; ++j)
    bf[j] = *reinterpret_cast<const bhalf8*>(bs_ + (wc * 4 + j) * 512 + rbase);

  __builtin_amdgcn_s_setprio(1);
#pragma unroll
  for (int i = 0; i < 4; ++i)
#pragma unroll
    for (int j = 0; j < 4; ++j) {
      if (MODE == 1)
        acc[i][j] = __builtin_amdgcn_mfma_f32_16x16x32_bf16(bf[j], af[i], acc[i][j], 0, 0, 0);
      else
        acc[i][j] = __builtin_amdgcn_mfma_f32_16x16x32_bf16(af[i], bf[j], acc[i][j], 0, 0, 0);
    }
  __builtin_amdgcn_s_setprio(0);

  GBAR();  // all waves' reads of this buffer drained -> overwrite safe

  stage32(A, Bt, as_w, bs_w, ks, row0, col0, wave, rA, cA, rB, cB);  // for t+2

  asm volatile("s_waitcnt vmcnt(3)" ::: "memory");  // t+1's 3 DMAs landed
  GBAR();
}

template <int MODE>
__global__ __launch_bounds__(512, 4) void gemm128x256(
    const unsigned short* __restrict__ A,
    const unsigned short* __restrict__ Bt,
    unsigned short* __restrict__ obf, float* __restrict__ of32,
    const float* __restrict__ bias) {
  __shared__ __align__(16) unsigned short As[2][128 * 32];
  __shared__ __align__(16) unsigned short Bs[2][256 * 32];
  const int tid  = threadIdx.x;
  const int lane = tid & 63;
  const int wave = tid >> 6;
  const int quad = lane >> 4;
  const int c16  = lane & 15;
  const int wr = wave >> 2, wc = wave & 3;

  // T1: XCD-aware remap (grid 8x64; linear wgid % 8 == XCD).
  const int wg  = blockIdx.y * 8 + blockIdx.x;
  const int xcd = wg & 7;
  const int idx = wg >> 3;                        // 0..63
  const int row0 = (xcd * 8 + (idx >> 3)) * 128;
  const int col0 = (idx & 7) * 256;

  // swizzled per-lane fragment base within a subtile (elems)
  const int rbase = c16 * 32 + ((quad * 8) ^ ((c16 >> 3) << 4));

  // staging decode: chunk c -> row = (c>>6)*16 + ((c>>2)&15),
  // col = ((c&3)<<3) ^ (((c>>5)&1)<<4)  (inverse of st_16x32 swizzle)
  int rA, cA, rB[2], cB[2];
  {
    int c = tid;
    rA = ((c >> 6) << 4) | ((c >> 2) & 15);
    cA = ((c & 3) << 3) ^ (((c >> 5) & 1) << 4);
#pragma unroll
    for (int p = 0; p < 2; ++p) {
      c = p * 512 + tid;
      rB[p] = ((c >> 6) << 4) | ((c >> 2) & 15);
      cB[p] = ((c & 3) << 3) ^ (((c >> 5) & 1) << 4);
    }
  }

  f32x4 acc[4][4];
#pragma unroll
  for (int i = 0; i < 4; ++i)
#pragma unroll
    for (int j = 0; j < 4; ++j)
#pragma unroll
      for (int r = 0; r < 4; ++r) acc[i][j][r] = 0.0f;

  // prologue: K-tile 0 -> buf0, K-tile 1 -> buf1
  stage32(A, Bt, As[0], Bs[0], 0,  row0, col0, wave, rA, cA, rB, cB);
  stage32(A, Bt, As[1], Bs[1], 32, row0, col0, wave, rA, cA, rB, cB);
  asm volatile("s_waitcnt vmcnt(3)" ::: "memory");  // K-tile 0 landed
  GBAR();

#pragma unroll 1
  for (int it = 0; it < 64; it += 2) {
    int ksA = it * 32 + 64;  if (ksA > 2016) ksA = 2016;  // tail: valid, never read
    int ksB = it * 32 + 96;  if (ksB > 2016) ksB = 2016;
    ktile32<MODE>(A, Bt, As[0], Bs[0], As[0], Bs[0], ksA, row0, col0,
                  wave, wr, wc, rbase, rA, cA, rB, cB, acc);
    ktile32<MODE>(A, Bt, As[1], Bs[1], As[1], Bs[1], ksB, row0, col0,
                  wave, wr, wc, rbase, rA, cA, rB, cB, acc);
  }

#pragma unroll
  for (int i = 0; i < 4; ++i)
#pragma unroll
    for (int j = 0; j < 4; ++j)
#pragma unroll
      for (int r = 0; r < 4; ++r) {
        float v = acc[i][j][r];
        if (MODE == 2) {
          int m = row0 + wr * 64 + i * 16 + quad * 4 + r;
          int n = col0 + wc * 64 + j * 16 + c16;
          of32[(size_t)m * 2048 + n] = v + bias[n];
        } else if (MODE == 0) {
          int m = row0 + wr * 64 + i * 16 + quad * 4 + r;
          int n = col0 + wc * 64 + j * 16 + c16;
          int b = m >> 11, s = m & 2047;
          int h = n >> 7,  d = n & 127;
          obf[(((size_t)(b * 16 + h)) * 2048 + s) * 128 + d] = f2bf(v);
        } else {
          int n = col0 + wc * 64 + j * 16 + quad * 4 + r;
          int m = row0 + wr * 64 + i * 16 + c16;
          int b = m >> 11, s = m & 2047;
          int h = n >> 7,  d = n & 127;
          obf[(((size_t)(b * 16 + h)) * 128 + d) * 2048 + s] = f2bf(v);
        }
      }
}

// ---------------- flash attention: S^T formulation ----------------
// Q,K: [b,h,s,128] bf16;  Vt: [b,h,128,s] bf16;  O: [b,s,h*128] bf16
// S^T = K*Q^T so softmax rows live per-lane; K staged with row-permutation rho
// so exp'd P values are directly the B-fragment of mfma for O^T = V^T * P^T.
// R6: T2 XOR swizzle replaces +8 pads (pads left rows 4-bank-strided: 16 lanes
// on 8 bank-groups -> 17.4M conflict cycles/dispatch ~= 20% of kernel time).
// Unpadded rows (256B/128B = bank-aligned) + 16B-chunk XOR with (row&7):
// reads spread (c16&7) over all 32 banks, 2-way only (free, m136).
// NOTE: register K/V double-buffering (T14) tried twice (R2/R4) -- spills
// (~1 GB scratch traffic); the +64 VGPRs don't fit launch_bounds(256,4).
#define LQK 128
#define LV   64
__global__ __launch_bounds__(256, 4) void flash_kernel(
    const unsigned short* __restrict__ Q,
    const unsigned short* __restrict__ K,
    const unsigned short* __restrict__ Vt,
    unsigned short* __restrict__ O) {
  const int tid  = threadIdx.x;
  const int lane = tid & 63;
  const int wave = tid >> 6;
  const int quad = lane >> 4;
  const int c16  = lane & 15;
  const int bh = blockIdx.x;                 // bh fast => heavy q-tiles spread first
  const int q0 = (31 - blockIdx.y) * 64;     // longest-first (causal tail fix)
  const int bb = bh >> 4, hh = bh & 15;
  const int qidx = q0 + wave * 16 + c16;
  const float SL = ATTN_SCALE * LOG2E;       // softmax in log2 domain

  __shared__ __align__(16) unsigned short Ks[64 * LQK];
  __shared__ __align__(16) unsigned short Vs[128 * LV];   // [d][t]

  // stage Q tile into Ks (overlay; Q frags read once), layout [t][d-chunk^swz]
  const unsigned short* Qg = Q + ((size_t)bh * 2048 + q0) * 128;
#pragma unroll
  for (int i = 0; i < 4; i++) {
    int chunk = i * 256 + tid;
    int t = chunk >> 4, dcc = chunk & 15;
    *reinterpret_cast<bhalf8*>(Ks + t * LQK + ((dcc ^ (t & 7)) << 3)) =
        *reinterpret_cast<const bhalf8*>(Qg + chunk * 8);
  }
  __syncthreads();
  bhalf8 qb[4];   // Q as B-operand: B[n=q=lane&15][k=quad*8+j]
  {
    const int qrow = wave * 16 + c16;
#pragma unroll
    for (int kk = 0; kk < 4; kk++)
      qb[kk] = *reinterpret_cast<const bhalf8*>(
          Ks + qrow * LQK + (((kk * 4 + quad) ^ (qrow & 7)) << 3));
  }

  f32x4 o_acc[8];   // O^T: col q=c16, row d=jd*16+quad*4+r
#pragma unroll
  for (int jd = 0; jd < 8; jd++)
#pragma unroll
    for (int r = 0; r < 4; r++) o_acc[jd][r] = 0.0f;
  float m_i = -__builtin_inff(), l_i = 0.0f;

  const unsigned short* Kbh = K  + (size_t)bh * 2048 * 128;
  const unsigned short* Vbh = Vt + (size_t)bh * 128 * 2048;

  const int nt = q0 / 64 + 1;
  for (int it = 0; it < nt; ++it) {
    const int t0 = it * 64;
    bhalf8 rk[4], rv[4];
#pragma unroll
    for (int i = 0; i < 4; i++) {
      int chunk = i * 256 + tid;
      int t = chunk >> 4, dc = (chunk & 15) << 3;               // K: [t][d]
      rk[i] = *reinterpret_cast<const bhalf8*>(Kbh + (size_t)(t0 + t) * 128 + dc);
      int d = chunk >> 3, tc = (chunk & 7) << 3;                // V^T: [d][t]
      rv[i] = *reinterpret_cast<const bhalf8*>(Vbh + (size_t)d * 2048 + t0 + tc);
    }
    __syncthreads();
#pragma unroll
    for (int i = 0; i < 4; i++) {
      int chunk = i * 256 + tid;
      int t = chunk >> 4, dcc = chunk & 15;
      // rho(t): makes P land in B-frag order (k=8*quad+j)
      int row = (((t >> 5) << 1) | ((t >> 2) & 1)) * 16 + ((t >> 3) & 3) * 4 + (t & 3);
      *reinterpret_cast<bhalf8*>(Ks + row * LQK + ((dcc ^ (row & 7)) << 3)) = rk[i];
      int d = chunk >> 3, tcc = chunk & 7;
      *reinterpret_cast<bhalf8*>(Vs + d * LV + ((tcc ^ (d & 7)) << 3)) = rv[i];
    }
    __syncthreads();

    // QK^T: kk-outer so st[0..3] interleave (no back-to-back dependent MFMA)
    f32x4 st[4];
#pragma unroll
    for (int tt = 0; tt < 4; tt++)
#pragma unroll
      for (int r = 0; r < 4; r++) st[tt][r] = 0.0f;
#pragma unroll
    for (int kk = 0; kk < 4; kk++)
#pragma unroll
      for (int tt = 0; tt < 4; tt++) {
        bhalf8 ka = *reinterpret_cast<const bhalf8*>(
            Ks + (tt * 16 + c16) * LQK + (((kk * 4 + quad) ^ (c16 & 7)) << 3));
        st[tt] = __builtin_amdgcn_mfma_f32_16x16x32_bf16(ka, qb[kk], st[tt], 0, 0, 0);
      }

    const bool diag = (t0 == q0);
    float pv[4][4];
    float rmax = -__builtin_inff();     // max over RAW scores (SL>0 commutes)
#pragma unroll
    for (int tt = 0; tt < 4; tt++)
#pragma unroll
      for (int r = 0; r < 4; r++) {
        float x = st[tt][r];
        if (diag) {
          int t = t0 + ((tt >> 1) << 5) + (quad << 3) + ((tt & 1) << 2) + r;
          if (t > qidx) x = -__builtin_inff();
        }
        pv[tt][r] = x;
        rmax = fmaxf(rmax, x);
      }
    rmax = fmaxf(rmax, __shfl_xor(rmax, 16));
    rmax = fmaxf(rmax, __shfl_xor(rmax, 32));
    const float pmax_s = rmax * SL;     // tile max in log2-scaled domain

    // T13 defer-max: only rescale when some row's max grew past threshold
    if (__any(pmax_s > m_i + 8.0f)) {
      const float mnew = fmaxf(m_i, pmax_s);
      const float alpha = exp2f(m_i - mnew);   // 0 when m_i=-inf
      m_i = mnew;
      l_i *= alpha;
#pragma unroll
      for (int jd = 0; jd < 8; jd++)
#pragma unroll
        for (int r = 0; r < 4; r++) o_acc[jd][r] *= alpha;
    }

    float rs = 0.0f;
#pragma unroll
    for (int tt = 0; tt < 4; tt++)
#pragma unroll
      for (int r = 0; r < 4; r++) {
        float p = exp2f(__builtin_fmaf(pv[tt][r], SL, -m_i));  // scale folded
        pv[tt][r] = p;
        rs += p;
      }
    l_i += rs;

    // O^T += V^T * P^T ; P^T B-frag packed in-register via v_perm
#pragma unroll
    for (int u = 0; u < 2; u++) {
      union { bhalf8 h; uint4 w; } pu;
      pu.w.x = pack_bf16_2(pv[2 * u][0],     pv[2 * u][1]);
      pu.w.y = pack_bf16_2(pv[2 * u][2],     pv[2 * u][3]);
      pu.w.z = pack_bf16_2(pv[2 * u + 1][0], pv[2 * u + 1][1]);
      pu.w.w = pack_bf16_2(pv[2 * u + 1][2], pv[2 * u + 1][3]);
#pragma unroll
      for (int jd = 0; jd < 8; jd++) {
        bhalf8 va = *reinterpret_cast<const bhalf8*>(
            Vs + (jd * 16 + c16) * LV + (((u * 4 + quad) ^ (c16 & 7)) << 3));
        o_acc[jd] = __builtin_amdgcn_mfma_f32_16x16x32_bf16(va, pu.h, o_acc[jd], 0, 0, 0);
      }
    }
  }

  l_i += __shfl_xor(l_i, 16);
  l_i += __shfl_xor(l_i, 32);
  const float inv = 1.0f / l_i;
#pragma unroll
  for (int jd = 0; jd < 8; jd++) {
    unsigned lo = (unsigned)f2bf(o_acc[jd][0] * inv) | ((unsigned)f2bf(o_acc[jd][1] * inv) << 16);
    unsigned hi = (unsigned)f2bf(o_acc[jd][2] * inv) | ((unsigned)f2bf(o_acc[jd][3] * inv) << 16);
    *reinterpret_cast<uint2*>(O + ((size_t)(bb * 2048 + qidx)) * 2048 + hh * 128 + jd * 16 + quad * 4) =
        make_uint2(lo, hi);
  }
}

extern "C" void kernel_launch(void* const* d_in, const int* in_sizes, int n_in,
                              void* d_out, int out_size, void* d_ws, size_t ws_size,
                              hipStream_t stream) {
  const float* x  = (const float*)d_in[0];
  const float* wq = (const float*)d_in[1];
  const float* wk = (const float*)d_in[2];
  const float* wv = (const float*)d_in[3];
  const float* wp = (const float*)d_in[4];
  const float* bp = (const float*)d_in[5];
  float* out = (float*)d_out;

  unsigned short* ws  = (unsigned short*)d_ws;
  const size_t ME = (size_t)8192 * 2048;
  const size_t EE = (size_t)2048 * 2048;
  unsigned short* xb  = ws;
  unsigned short* wqb = xb  + ME;
  unsigned short* wkb = wqb + EE;
  unsigned short* wvb = wkb + EE;
  unsigned short* wpb = wvb + EE;
  unsigned short* Qb  = wpb + EE;          // [b,h,s,d]
  unsigned short* Kb  = Qb  + ME;          // [b,h,s,d]
  unsigned short* Vtb = Kb  + ME;          // [b,h,d,s]
  unsigned short* Ob  = Vtb + ME;          // [b,s,h*d]

  cvt_kernel<<<16384, 256, 0, stream>>>(x,  xb,  (int)(ME / 4));
  cvt_kernel<<<4096,  256, 0, stream>>>(wq, wqb, (int)(EE / 4));
  cvt_kernel<<<4096,  256, 0, stream>>>(wk, wkb, (int)(EE / 4));
  cvt_kernel<<<4096,  256, 0, stream>>>(wv, wvb, (int)(EE / 4));
  cvt_kernel<<<4096,  256, 0, stream>>>(wp, wpb, (int)(EE / 4));

  dim3 g2(8, 64);  // N/256 x M/128 = 512 blocks = 2/CU, no tail
  gemm128x256<0><<<g2, 512, 0, stream>>>(xb, wqb, Qb,  nullptr, nullptr);
  gemm128x256<0><<<g2, 512, 0, stream>>>(xb, wkb, Kb,  nullptr, nullptr);
  gemm128x256<1><<<g2, 512, 0, stream>>>(xb, wvb, Vtb, nullptr, nullptr);

  flash_kernel<<<dim3(64, 32), 256, 0, stream>>>(Qb, Kb, Vtb, Ob);

  gemm128x256<2><<<g2, 512, 0, stream>>>(Ob, wpb, nullptr, out, bp);
}